// Round 5
// baseline (7297.361 us; speedup 1.0000x reference)
//
#include <hip/hip_runtime.h>
#include <cstdint>
#include <cstddef>

#define T_STEPS 2048
#define BATCH   32
#define VDIM    512
#define HDIM    512
#define SLICES  8      // WGs per batch element
#define COLS    64     // output columns per WG
#define KPT     64     // k-range per wave (HDIM / SLICES)

typedef _Float16 half2v __attribute__((ext_vector_type(2)));
typedef _Float16 half8v __attribute__((ext_vector_type(8)));

__device__ __forceinline__ float dot2h(half2v a, half2v b, float c) {
#if __has_builtin(__builtin_amdgcn_fdot2)
    return __builtin_amdgcn_fdot2(a, b, c, false);
#else
    return fmaf((float)a.x, (float)b.x, fmaf((float)a.y, (float)b.y, c));
#endif
}

// slow path: agent-scope tagged load/store (MALL coherence point; always correct)
__device__ __forceinline__ unsigned long long loadt(const unsigned long long* p) {
    return __hip_atomic_load(p, __ATOMIC_RELAXED, __HIP_MEMORY_SCOPE_AGENT);
}
// fast path: sc0 (L1-bypass, L2-hit) 8-B load/store — visible across CUs of the
// SAME XCD via the shared L2. Single dwordx2 instruction -> 8-B atomicity.
__device__ __forceinline__ unsigned long long fload(const unsigned long long* p) {
    unsigned long long r;
    asm volatile("global_load_dwordx2 %0, %1, off sc0\n\ts_waitcnt vmcnt(0)"
                 : "=v"(r) : "v"(p) : "memory");
    return r;
}
__device__ __forceinline__ void fstore(unsigned long long* p, unsigned long long x) {
    asm volatile("global_store_dwordx2 %0, %1, off sc0" :: "v"(p), "v"(x) : "memory");
}

__device__ __forceinline__ void publish(unsigned long long* fast, unsigned long long* slow,
                                        float v, unsigned tag) {
    unsigned long long x = ((unsigned long long)tag << 32) | (unsigned)__float_as_uint(v);
    fstore(fast, x);                                       // same-XCD consumers see this in ~L2 RT
    __hip_atomic_store(slow, x, __ATOMIC_RELAXED, __HIP_MEMORY_SCOPE_AGENT);  // guaranteed path
}

__device__ __forceinline__ float poll_tag(const unsigned long long* fast,
                                          const unsigned long long* slow, unsigned want) {
    for (;;) {
        unsigned long long v = fload(fast);
        if ((unsigned)(v >> 32) == want) return __uint_as_float((unsigned)v);
        v = fload(fast);
        if ((unsigned)(v >> 32) == want) return __uint_as_float((unsigned)v);
        v = loadt(slow);                                   // progress guarantee (any placement)
        if ((unsigned)(v >> 32) == want) return __uint_as_float((unsigned)v);
    }
}

// ---------------- Phase 1: x-projection GEMM ----
__global__ __launch_bounds__(256)
void xproj_gemm(const float* __restrict__ X,
                const float* __restrict__ W0, const float* __restrict__ b0,
                const float* __restrict__ W1, const float* __restrict__ b1,
                const float* __restrict__ W2, const float* __restrict__ b2,
                float* __restrict__ xp, int M)
{
    const int g = blockIdx.z;
    const float* W    = (g == 0) ? W0 : (g == 1) ? W1 : W2;
    const float* bias = (g == 0) ? b0 : (g == 1) ? b1 : b2;
    float* out = xp + (size_t)g * M * HDIM;

    __shared__ float As[16][68];
    __shared__ float Bs[16][64];

    const int tid = threadIdx.x;
    const int tx = tid & 15;
    const int ty = tid >> 4;
    const int row0 = blockIdx.y * 64;
    const int n0   = blockIdx.x * 64;

    const int lm = tid >> 2;
    const int lk = (tid & 3) * 4;
    const int bk = tid >> 4;
    const int bn = (tid & 15) * 4;

    float acc[4][4] = {};

    for (int k0 = 0; k0 < VDIM; k0 += 16) {
        float4 av = *(const float4*)&X[(size_t)(row0 + lm) * VDIM + k0 + lk];
        float4 bv = *(const float4*)&W[(size_t)(k0 + bk) * HDIM + n0 + bn];
        __syncthreads();
        As[lk + 0][lm] = av.x;
        As[lk + 1][lm] = av.y;
        As[lk + 2][lm] = av.z;
        As[lk + 3][lm] = av.w;
        *(float4*)&Bs[bk][bn] = bv;
        __syncthreads();
        #pragma unroll
        for (int kk = 0; kk < 16; ++kk) {
            float4 a = *(const float4*)&As[kk][ty * 4];
            float4 b = *(const float4*)&Bs[kk][tx * 4];
            float ar[4] = {a.x, a.y, a.z, a.w};
            float br[4] = {b.x, b.y, b.z, b.w};
            #pragma unroll
            for (int i = 0; i < 4; ++i)
                #pragma unroll
                for (int j = 0; j < 4; ++j)
                    acc[i][j] += ar[i] * br[j];
        }
    }

    float4 bb = *(const float4*)&bias[n0 + tx * 4];
    #pragma unroll
    for (int i = 0; i < 4; ++i) {
        const int row = row0 + ty * 4 + i;
        float4 o;
        o.x = acc[i][0] + bb.x;
        o.y = acc[i][1] + bb.y;
        o.z = acc[i][2] + bb.z;
        o.w = acc[i][3] + bb.w;
        *(float4*)&out[(size_t)row * HDIM + n0 + tx * 4] = o;
    }
}

// ---------------- Phase 2: scan, dual-path (XCD-L2 fast / MALL slow) exchange ----
// Grid 256 WGs: blockIdx = b + 32*s -> blockIdx%8 = b%8, so all 8 slices of a
// batch land on ONE XCD under round-robin dispatch -> fast path hits shared L2.
__global__ __launch_bounds__(512)
__attribute__((amdgpu_waves_per_eu(2, 2)))
void gru_scan4(const float* __restrict__ xp,
               const float* __restrict__ Wrh, const float* __restrict__ Wnh,
               const float* __restrict__ Wzh,
               const float* __restrict__ state, float* __restrict__ out,
               unsigned long long* __restrict__ hS, unsigned long long* __restrict__ uS,
               unsigned long long* __restrict__ hF, unsigned long long* __restrict__ uF,
               int t0, int nt, int M)
{
    const int b   = blockIdx.x & (BATCH - 1);
    const int s   = blockIdx.x >> 5;
    const int tid = threadIdx.x;
    const int c   = tid & (COLS - 1);
    const int j   = tid >> 6;
    const int n   = s * COLS + c;          // own output column (wave 0)

    __shared__ __align__(16) _Float16 hlds[HDIM];
    __shared__ __align__(16) _Float16 ulds[HDIM];
    __shared__ float redR[SLICES][COLS];
    __shared__ float redN[SLICES][COLS];
    __shared__ float redZ[SLICES][COLS];

    // ---- one-time: weights -> f16x2 registers (96 packed VGPRs) ----
    half2v w2r[KPT / 2], w2n[KPT / 2], w2z[KPT / 2];
    {
        const size_t coloff = (size_t)s * COLS + c;
        const float* pr = Wrh + (size_t)j * KPT * HDIM + coloff;
        const float* pn = Wnh + (size_t)j * KPT * HDIM + coloff;
        const float* pz = Wzh + (size_t)j * KPT * HDIM + coloff;
        #pragma unroll
        for (int q = 0; q < KPT / 2; ++q) {
            half2v r, nn, z;
            r.x  = (_Float16)pr[(size_t)(2 * q) * HDIM];
            r.y  = (_Float16)pr[(size_t)(2 * q + 1) * HDIM];
            nn.x = (_Float16)pn[(size_t)(2 * q) * HDIM];
            nn.y = (_Float16)pn[(size_t)(2 * q + 1) * HDIM];
            z.x  = (_Float16)pz[(size_t)(2 * q) * HDIM];
            z.y  = (_Float16)pz[(size_t)(2 * q + 1) * HDIM];
            w2r[q] = r; w2n[q] = nn; w2z[q] = z;
        }
        #pragma unroll
        for (int q = 0; q < KPT / 2; ++q)
            asm volatile("" : "+v"(w2r[q]), "+v"(w2n[q]), "+v"(w2z[q]));
    }

    const size_t bb32 = (size_t)b * HDIM;
    unsigned long long* hSb = hS + bb32;
    unsigned long long* uSb = uS + bb32;
    unsigned long long* hFb = hF + bb32;
    unsigned long long* uFb = uF + bb32;
    const size_t gs = (size_t)M * HDIM;

    float hcv = 0.f;                       // wave0: own column's h, carried in-register

    for (int tt = 0; tt < nt; ++tt) {
        const int t = t0 + tt;

        // xp prefetch (independent of exchange)
        float xr = 0.f, xnn = 0.f, xz = 0.f;
        const size_t rb = ((size_t)tt * BATCH + b) * HDIM;
        if (tid < COLS) {
            xr  = xp[rb + n];
            xnn = xp[gs + rb + n];
            xz  = xp[2 * gs + rb + n];
        }

        // ---- acquire h[own k-slot] ----
        float hv;
        if (t == 0) {
            hv = state[bb32 + tid];
            if (tid < COLS) hcv = state[bb32 + n];
        } else {
            hv = poll_tag(hFb + tid, hSb + tid, (unsigned)t);
            if (tt == 0 && tid < COLS)     // chunk restart: recover own-column carry
                hcv = poll_tag(hFb + n, hSb + n, (unsigned)t);
        }

        // wave-local stage (wave j writes exactly the range it reads)
        hlds[tid] = (_Float16)hv;
        asm volatile("s_waitcnt lgkmcnt(0)" ::: "memory");
        __builtin_amdgcn_sched_barrier(0);

        // ---- R partials over own k-range ----
        {
            float aR = 0.f;
            const half8v* hp = (const half8v*)&hlds[j * KPT];
            #pragma unroll
            for (int q = 0; q < KPT / 8; ++q) {
                half8v h8 = hp[q];
                half2v p0 = {h8[0], h8[1]}, p1 = {h8[2], h8[3]};
                half2v p2 = {h8[4], h8[5]}, p3 = {h8[6], h8[7]};
                aR = dot2h(p0, w2r[4 * q + 0], aR);
                aR = dot2h(p1, w2r[4 * q + 1], aR);
                aR = dot2h(p2, w2r[4 * q + 2], aR);
                aR = dot2h(p3, w2r[4 * q + 3], aR);
            }
            redR[j][c] = aR;
        }
        __syncthreads();                               // barrier A

        // ---- wave0: reduce, u = h*sigmoid, publish (other waves fall through to poll) ----
        if (tid < COLS) {
            float sR = 0.f;
            #pragma unroll
            for (int jj = 0; jj < SLICES; ++jj) sR += redR[jj][c];
            float R = 1.f / (1.f + __expf(-(xr + sR)));
            publish(uFb + n, uSb + n, hcv * R, (unsigned)(t + 1));
        }

        // ---- all waves poll own u k-slot, stage wave-locally ----
        ulds[tid] = (_Float16)poll_tag(uFb + tid, uSb + tid, (unsigned)(t + 1));
        asm volatile("s_waitcnt lgkmcnt(0)" ::: "memory");
        __builtin_amdgcn_sched_barrier(0);

        // ---- N,Z partials ----
        {
            float aN = 0.f, aZ = 0.f;
            const half8v* up = (const half8v*)&ulds[j * KPT];
            #pragma unroll
            for (int q = 0; q < KPT / 8; ++q) {
                half8v u8 = up[q];
                half2v p0 = {u8[0], u8[1]}, p1 = {u8[2], u8[3]};
                half2v p2 = {u8[4], u8[5]}, p3 = {u8[6], u8[7]};
                aN = dot2h(p0, w2n[4 * q + 0], aN);
                aZ = dot2h(p0, w2z[4 * q + 0], aZ);
                aN = dot2h(p1, w2n[4 * q + 1], aN);
                aZ = dot2h(p1, w2z[4 * q + 1], aZ);
                aN = dot2h(p2, w2n[4 * q + 2], aN);
                aZ = dot2h(p2, w2z[4 * q + 2], aZ);
                aN = dot2h(p3, w2n[4 * q + 3], aN);
                aZ = dot2h(p3, w2z[4 * q + 3], aZ);
            }
            redN[j][c] = aN;
            redZ[j][c] = aZ;
        }
        __syncthreads();                               // barrier B

        // ---- wave0: h_new, publish + output; carry own column in register ----
        if (tid < COLS) {
            float sN = 0.f, sZ = 0.f;
            #pragma unroll
            for (int jj = 0; jj < SLICES; ++jj) { sN += redN[jj][c]; sZ += redZ[jj][c]; }
            float e  = __expf(2.f * (xnn + sN));
            float Hc = 1.f - 2.f / (e + 1.f);          // tanh
            float Z  = 1.f / (1.f + __expf(-(xz + sZ)));
            float hnew = Z * hcv + (1.f - Z) * Hc;
            publish(hFb + n, hSb + n, hnew, (unsigned)(t + 1));
            __builtin_nontemporal_store(hnew, out + (size_t)t * BATCH * HDIM + bb32 + n);
            hcv = hnew;
            if (t == T_STEPS - 1)
                out[(size_t)T_STEPS * BATCH * HDIM + bb32 + n] = hnew;
        }
    }
}

extern "C" void kernel_launch(void* const* d_in, const int* in_sizes, int n_in,
                              void* d_out, int out_size, void* d_ws, size_t ws_size,
                              hipStream_t stream) {
    const float* inputs   = (const float*)d_in[0];
    const float* state    = (const float*)d_in[1];
    const float* W_reset  = (const float*)d_in[2];
    const float* b_reset  = (const float*)d_in[3];
    const float* W_net    = (const float*)d_in[4];
    const float* b_net    = (const float*)d_in[5];
    const float* W_update = (const float*)d_in[6];
    const float* b_update = (const float*)d_in[7];
    float* out = (float*)d_out;

    // tail: 4 tagged buffers (hSlow, uSlow, hFast, uFast), 128 KB each
    const size_t buf_elems = (size_t)BATCH * HDIM;
    const size_t tail_bytes = 4ull * buf_elems * 8;
    size_t tail_base = (ws_size - tail_bytes) & ~(size_t)255;
    char* base = (char*)d_ws;
    float* xp = (float*)base;
    unsigned long long* hS = (unsigned long long*)(base + tail_base);
    unsigned long long* uS = hS + buf_elems;
    unsigned long long* hF = uS + buf_elems;
    unsigned long long* uF = hF + buf_elems;

    const size_t per_t = 3ull * BATCH * HDIM * sizeof(float);
    int C = (int)(tail_base / per_t);
    if (C > T_STEPS) C = T_STEPS;
    C &= ~1;
    if (C < 2) C = 2;

    // all tags to 0xFFFFFFFF (never a valid step) each call -> deterministic replays
    hipMemsetAsync(hS, 0xFF, tail_bytes, stream);

    for (int t0 = 0; t0 < T_STEPS; t0 += C) {
        const int nt = (T_STEPS - t0 < C) ? (T_STEPS - t0) : C;
        const int M  = nt * BATCH;

        dim3 g1(HDIM / 64, M / 64, 3);
        xproj_gemm<<<g1, 256, 0, stream>>>(inputs + (size_t)t0 * BATCH * VDIM,
                                           W_reset, b_reset,
                                           W_net,   b_net,
                                           W_update, b_update,
                                           xp, M);

        gru_scan4<<<BATCH * SLICES, 512, 0, stream>>>(
            xp,
            W_reset  + (size_t)VDIM * HDIM,
            W_net    + (size_t)VDIM * HDIM,
            W_update + (size_t)VDIM * HDIM,
            state, out, hS, uS, hF, uF, t0, nt, M);
    }
}